// Round 7
// baseline (18.983 us; speedup 1.0000x reference)
//
#include <hip/hip_runtime.h>
#include <math.h>

typedef float f2v __attribute__((ext_vector_type(2)));

#define BATCH 4096
#define NPAIRF 2016.0f

__device__ __forceinline__ f2v relu2(f2v t) {
    t.x = fmaxf(t.x, 0.0f);
    t.y = fmaxf(t.y, 0.0f);
    return t;
}

// DPP-based wave64 sum (VALU pipe, no DS traffic). Total lands in lane 63.
template <int CTRL>
__device__ __forceinline__ float dpp_add(float x) {
    int y = __builtin_amdgcn_update_dpp(0, __builtin_bit_cast(int, x), CTRL, 0xf, 0xf, true);
    return x + __builtin_bit_cast(float, y);
}
__device__ __forceinline__ float wave_sum63(float x) {
    x = dpp_add<0x111>(x);  // row_shr:1
    x = dpp_add<0x112>(x);  // row_shr:2
    x = dpp_add<0x114>(x);  // row_shr:4
    x = dpp_add<0x118>(x);  // row_shr:8
    x = dpp_add<0x142>(x);  // row_bcast:15
    x = dpp_add<0x143>(x);  // row_bcast:31 -> lane63 = full sum
    return x;
}

// round-half-up bf16 pack: dword = [hi: bf16(b)][lo: bf16(a)]
__device__ __forceinline__ unsigned pack_bf16(float a, float b) {
    unsigned ua = __builtin_bit_cast(unsigned, a) + 0x8000u;
    unsigned ub = __builtin_bit_cast(unsigned, b) + 0x8000u;
    return (ua >> 16) | (ub & 0xffff0000u);
}
__device__ __forceinline__ f2v unpack_bf16(unsigned w) {
    f2v r;
    r.x = __builtin_bit_cast(float, w << 16);
    r.y = __builtin_bit_cast(float, w & 0xffff0000u);
    return r;
}

__global__ __launch_bounds__(256, 4) void akan_kernel(
    const float* __restrict__ x,
    const float* __restrict__ phi_W1, const float* __restrict__ phi_b1,
    const float* __restrict__ phi_W2, const float* __restrict__ phi_b2,
    const float* __restrict__ attn_W, const float* __restrict__ attn_b,
    const float* __restrict__ psi_W1, const float* __restrict__ psi_b1,
    const float* __restrict__ psi_W2, const float* __restrict__ psi_b2,
    float* __restrict__ out)
{
    // Per-wave bf16 row store (dword offsets within the wave's 640-dword slab):
    //   [0,256)    uMain: row p comps 0..7 at 4p   (stride 16 B -> quadbank = p%8, conflict-free)
    //   [256,320)  uC:    row p comps 8,9  at 256+p (stride 4 B -> bank = p%32, conflict-free)
    //   [320,576)  vMain
    //   [576,640)  vC
    __shared__ __align__(16) unsigned lds[4 * 640];   // 10 KB/block

    const int lane = threadIdx.x & 63;
    const int wave = threadIdx.x >> 6;
    const int b = blockIdx.x * 4 + wave;
    unsigned* const lw = lds + wave * 640;

    // ---- phi: per-feature scalar MLP (input dim 1), exact f32 ----
    const float xv = x[b * 64 + lane];
    float phi_out[5];
    #pragma unroll
    for (int o = 0; o < 5; ++o) phi_out[o] = phi_b2[o];
    #pragma unroll
    for (int k = 0; k < 10; ++k) {
        const float h = fmaxf(fmaf(xv, phi_W1[k], phi_b1[k]), 0.0f);
        #pragma unroll
        for (int o = 0; o < 5; ++o) phi_out[o] = fmaf(h, phi_W2[k * 5 + o], phi_out[o]);
    }

    // ---- attention softmax over features (shift-invariant; scores ~0.15, skip max) ----
    float score = attn_b[0];
    #pragma unroll
    for (int o = 0; o < 5; ++o) score = fmaf(phi_out[o], attn_W[o], score);
    const float e = __expf(score);
    const float t63 = wave_sum63(e);
    const float ssum = __builtin_bit_cast(float,
        __builtin_amdgcn_readlane(__builtin_bit_cast(int, t63), 63));
    const float wgt = e * __builtin_amdgcn_rcpf(ssum);

    // ---- psi layer-1 split: u (rows 0..4 of psi_W1, +b1) / v (rows 5..9) ----
    float w[5];
    #pragma unroll
    for (int o = 0; o < 5; ++o) w[o] = phi_out[o] * wgt;

    float u[10], v[10];
    #pragma unroll
    for (int hh = 0; hh < 10; ++hh) {
        float uu = psi_b1[hh];
        float vv = 0.0f;
        #pragma unroll
        for (int o = 0; o < 5; ++o) {
            uu = fmaf(w[o], psi_W1[o * 10 + hh], uu);
            vv = fmaf(w[o], psi_W1[(5 + o) * 10 + hh], vv);
        }
        u[hh] = uu; v[hh] = vv;
    }

    // ---- stage rows as bf16 (wave-private; same-wave DS ordering, no barrier) ----
    {
        uint4 mu, mv;
        mu.x = pack_bf16(u[0], u[1]); mu.y = pack_bf16(u[2], u[3]);
        mu.z = pack_bf16(u[4], u[5]); mu.w = pack_bf16(u[6], u[7]);
        mv.x = pack_bf16(v[0], v[1]); mv.y = pack_bf16(v[2], v[3]);
        mv.z = pack_bf16(v[4], v[5]); mv.w = pack_bf16(v[6], v[7]);
        *(uint4*)&lw[4 * lane]       = mu;
        lw[256 + lane]               = pack_bf16(u[8], u[9]);
        *(uint4*)&lw[320 + 4 * lane] = mv;
        lw[576 + lane]               = pack_bf16(v[8], v[9]);
    }

    // ---- local operands packed f2v (exact f32) ----
    f2v U[5], V[5], S[5];
    #pragma unroll
    for (int j = 0; j < 5; ++j) {
        U[j] = (f2v){u[2 * j], u[2 * j + 1]};
        V[j] = (f2v){v[2 * j], v[2 * j + 1]};
        S[j] = (f2v){0.0f, 0.0f};
    }

    // ---- pair loop, wrap-around, fully unrolled ----
    #pragma unroll
    for (int d = 1; d <= 31; ++d) {
        const int pl = lane + d;
        const int m = pl & 63;
        const bool wrapped = pl >= 64;       // remote is u-region, local is V
        const unsigned* rb = wrapped ? lw : (lw + 320);
        const uint4 q = *(const uint4*)(rb + 4 * m);
        const unsigned c = rb[256 + m];
        const f2v R0 = unpack_bf16(q.x), R1 = unpack_bf16(q.y),
                  R2 = unpack_bf16(q.z), R3 = unpack_bf16(q.w),
                  R4 = unpack_bf16(c);
        const f2v L0 = wrapped ? V[0] : U[0];
        const f2v L1 = wrapped ? V[1] : U[1];
        const f2v L2 = wrapped ? V[2] : U[2];
        const f2v L3 = wrapped ? V[3] : U[3];
        const f2v L4 = wrapped ? V[4] : U[4];
        S[0] += relu2(L0 + R0);
        S[1] += relu2(L1 + R1);
        S[2] += relu2(L2 + R2);
        S[3] += relu2(L3 + R3);
        S[4] += relu2(L4 + R4);
    }
    if (lane < 32) {   // d = 32: pair (lane, lane+32), counted once, never wraps
        const int m = lane + 32;
        const unsigned* rb = lw + 320;
        const uint4 q = *(const uint4*)(rb + 4 * m);
        const unsigned c = rb[256 + m];
        S[0] += relu2(U[0] + unpack_bf16(q.x));
        S[1] += relu2(U[1] + unpack_bf16(q.y));
        S[2] += relu2(U[2] + unpack_bf16(q.z));
        S[3] += relu2(U[3] + unpack_bf16(q.w));
        S[4] += relu2(U[4] + unpack_bf16(c));
    }

    // ---- psi layer-2 first (linear), then DPP-reduce 5 values (VALU pipe) ----
    float sv[10];
    #pragma unroll
    for (int j = 0; j < 5; ++j) { sv[2 * j] = S[j].x; sv[2 * j + 1] = S[j].y; }

    float po[5];
    #pragma unroll
    for (int o = 0; o < 5; ++o) {
        float acc = 0.0f;
        #pragma unroll
        for (int hh = 0; hh < 10; ++hh)
            acc = fmaf(sv[hh], psi_W2[hh * 5 + o], acc);
        po[o] = wave_sum63(acc);
    }

    if (lane == 63) {
        #pragma unroll
        for (int o = 0; o < 5; ++o)
            out[b * 5 + o] = fmaf(NPAIRF, psi_b2[o], po[o]);
    }
}

extern "C" void kernel_launch(void* const* d_in, const int* in_sizes, int n_in,
                              void* d_out, int out_size, void* d_ws, size_t ws_size,
                              hipStream_t stream) {
    const float* x      = (const float*)d_in[0];
    const float* phi_W1 = (const float*)d_in[1];
    const float* phi_b1 = (const float*)d_in[2];
    const float* phi_W2 = (const float*)d_in[3];
    const float* phi_b2 = (const float*)d_in[4];
    const float* attn_W = (const float*)d_in[5];
    const float* attn_b = (const float*)d_in[6];
    const float* psi_W1 = (const float*)d_in[7];
    const float* psi_b1 = (const float*)d_in[8];
    const float* psi_W2 = (const float*)d_in[9];
    const float* psi_b2 = (const float*)d_in[10];
    float* outp = (float*)d_out;

    dim3 grid(BATCH / 4);   // 4 waves (one sample each) per 256-thread block
    dim3 block(256);
    akan_kernel<<<grid, block, 0, stream>>>(x, phi_W1, phi_b1, phi_W2, phi_b2,
                                            attn_W, attn_b, psi_W1, psi_b1,
                                            psi_W2, psi_b2, outp);
}

// Round 9
// 16.095 us; speedup vs baseline: 1.1794x; 1.1794x over previous
//
#include <hip/hip_runtime.h>
#include <math.h>

typedef float f2v __attribute__((ext_vector_type(2)));
typedef _Float16 h2 __attribute__((ext_vector_type(2)));

#define BATCH 4096
#define NPAIRF 2016.0f

// DPP-based wave64 sum (VALU pipe). Total lands in lane 63.
template <int CTRL>
__device__ __forceinline__ float dpp_add(float x) {
    int y = __builtin_amdgcn_update_dpp(0, __builtin_bit_cast(int, x), CTRL, 0xf, 0xf, true);
    return x + __builtin_bit_cast(float, y);
}
__device__ __forceinline__ float wave_sum63(float x) {
    x = dpp_add<0x111>(x);  // row_shr:1
    x = dpp_add<0x112>(x);  // row_shr:2
    x = dpp_add<0x114>(x);  // row_shr:4
    x = dpp_add<0x118>(x);  // row_shr:8
    x = dpp_add<0x142>(x);  // row_bcast:15
    x = dpp_add<0x143>(x);  // row_bcast:31 -> lane63 = full sum
    return x;
}

__device__ __forceinline__ h2 pkmax(h2 a, h2 b) {
    h2 r;
    asm("v_pk_max_f16 %0, %1, %2" : "=v"(r) : "v"(a), "v"(b));
    return r;
}
__device__ __forceinline__ h2 ash2(unsigned w) { return __builtin_bit_cast(h2, w); }

// LDS layout per wave (6144 B): two sample slabs of 3072 B.
// Slab: u-region @0, v-region @1536. Region: arr01[64]x8B @0, arr23 @512, arr4 @1024 (stride 8).
__global__ __launch_bounds__(256, 2) void akan_kernel(
    const float* __restrict__ x,
    const float* __restrict__ phi_W1, const float* __restrict__ phi_b1,
    const float* __restrict__ phi_W2, const float* __restrict__ phi_b2,
    const float* __restrict__ attn_W, const float* __restrict__ attn_b,
    const float* __restrict__ psi_W1, const float* __restrict__ psi_b1,
    const float* __restrict__ psi_W2, const float* __restrict__ psi_b2,
    float* __restrict__ out)
{
    __shared__ __align__(16) char lds[4 * 6144];
    const int lane = threadIdx.x & 63;
    const int wave = threadIdx.x >> 6;
    const int b0 = (blockIdx.x * 4 + wave) * 2;   // 2 samples per wave
    char* const wslab = lds + wave * 6144;

    h2 U[2][5], V[2][5], S16[2][5];
    f2v S32[2][5];

    // ================= prologue: per-sample phi/attn/psi1 (exact f32) =================
    #pragma unroll
    for (int k = 0; k < 2; ++k) {
        const float xv = x[(b0 + k) * 64 + lane];
        float phi_out[5];
        #pragma unroll
        for (int o = 0; o < 5; ++o) phi_out[o] = phi_b2[o];
        #pragma unroll
        for (int kk = 0; kk < 10; ++kk) {
            const float h = fmaxf(fmaf(xv, phi_W1[kk], phi_b1[kk]), 0.0f);
            #pragma unroll
            for (int o = 0; o < 5; ++o) phi_out[o] = fmaf(h, phi_W2[kk * 5 + o], phi_out[o]);
        }
        float score = attn_b[0];
        #pragma unroll
        for (int o = 0; o < 5; ++o) score = fmaf(phi_out[o], attn_W[o], score);
        const float e = __expf(score);   // shift-invariant softmax; scores tiny (verified 3 rounds)
        const float t63 = wave_sum63(e);
        const float ssum = __builtin_bit_cast(float,
            __builtin_amdgcn_readlane(__builtin_bit_cast(int, t63), 63));
        const float wgt = e * __builtin_amdgcn_rcpf(ssum);

        float w[5];
        #pragma unroll
        for (int o = 0; o < 5; ++o) w[o] = phi_out[o] * wgt;

        float u[10], v[10];
        #pragma unroll
        for (int hh = 0; hh < 10; ++hh) {
            float uu = psi_b1[hh];
            float vv = 0.0f;
            #pragma unroll
            for (int o = 0; o < 5; ++o) {
                uu = fmaf(w[o], psi_W1[o * 10 + hh], uu);
                vv = fmaf(w[o], psi_W1[(5 + o) * 10 + hh], vv);
            }
            u[hh] = uu; v[hh] = vv;
        }
        // pack to fp16 (RTE via scalar cvt) + init accumulators
        #pragma unroll
        for (int j = 0; j < 5; ++j) {
            U[k][j] = (h2){(_Float16)u[2 * j], (_Float16)u[2 * j + 1]};
            V[k][j] = (h2){(_Float16)v[2 * j], (_Float16)v[2 * j + 1]};
            S16[k][j] = (h2){0, 0};
            S32[k][j] = (f2v){0.0f, 0.0f};
        }
        // stage rows (wave-private; same-wave DS ordering, no barrier)
        char* slab = wslab + k * 3072;
        uint2 q;
        q.x = __builtin_bit_cast(unsigned, U[k][0]); q.y = __builtin_bit_cast(unsigned, U[k][1]);
        *(uint2*)(slab + lane * 8) = q;
        q.x = __builtin_bit_cast(unsigned, U[k][2]); q.y = __builtin_bit_cast(unsigned, U[k][3]);
        *(uint2*)(slab + 512 + lane * 8) = q;
        *(unsigned*)(slab + 1024 + lane * 8) = __builtin_bit_cast(unsigned, U[k][4]);
        q.x = __builtin_bit_cast(unsigned, V[k][0]); q.y = __builtin_bit_cast(unsigned, V[k][1]);
        *(uint2*)(slab + 1536 + lane * 8) = q;
        q.x = __builtin_bit_cast(unsigned, V[k][2]); q.y = __builtin_bit_cast(unsigned, V[k][3]);
        *(uint2*)(slab + 2048 + lane * 8) = q;
        *(unsigned*)(slab + 2560 + lane * 8) = __builtin_bit_cast(unsigned, V[k][4]);
    }

    // ================= pair loop: wrap-around d=1..31 + half d=32 =================
    // unwrapped (lane+d<64): pair (lane, lane+d): local=U, remote=v-region row lane+d
    // wrapped: pair (lane+d-64, lane): local=V, remote=u-region row lane+d-64
    // One base pointer + compile-time immediates serves all 6 loads (both samples).
    const char* const rowb = wslab + lane * 8;

    #define PROC(k, r0, r1, r2, r3, r4)                                  \
        {                                                                \
            const h2 L0 = uw ? U[k][0] : V[k][0];                        \
            const h2 L1 = uw ? U[k][1] : V[k][1];                        \
            const h2 L2 = uw ? U[k][2] : V[k][2];                        \
            const h2 L3 = uw ? U[k][3] : V[k][3];                        \
            const h2 L4 = uw ? U[k][4] : V[k][4];                        \
            S16[k][0] = pkmax(S16[k][0] + (L0 + ash2(r0)), S16[k][0]);   \
            S16[k][1] = pkmax(S16[k][1] + (L1 + ash2(r1)), S16[k][1]);   \
            S16[k][2] = pkmax(S16[k][2] + (L2 + ash2(r2)), S16[k][2]);   \
            S16[k][3] = pkmax(S16[k][3] + (L3 + ash2(r3)), S16[k][3]);   \
            S16[k][4] = pkmax(S16[k][4] + (L4 + ash2(r4)), S16[k][4]);   \
        }
    #define PROMOTE()                                                    \
        _Pragma("unroll") for (int k = 0; k < 2; ++k)                    \
        _Pragma("unroll") for (int j = 0; j < 5; ++j) {                  \
            S32[k][j] += (f2v){(float)S16[k][j].x, (float)S16[k][j].y};  \
            S16[k][j] = (h2){0, 0};                                      \
        }

    #pragma unroll
    for (int d = 1; d <= 31; ++d) {
        const bool uw = lane < (64 - d);
        const char* p = (uw ? rowb + 1536 : rowb - 512) + 8 * d;
        const uint2    a01 = *(const uint2*)(p);
        const uint2    a23 = *(const uint2*)(p + 512);
        const unsigned a4  = *(const unsigned*)(p + 1024);
        const uint2    c01 = *(const uint2*)(p + 3072);
        const uint2    c23 = *(const uint2*)(p + 3584);
        const unsigned c4  = *(const unsigned*)(p + 4096);
        PROC(0, a01.x, a01.y, a23.x, a23.y, a4);
        PROC(1, c01.x, c01.y, c23.x, c23.y, c4);
        if (d == 16) { PROMOTE(); }   // fp16 chunk cap: 16 terms
    }
    if (lane < 32) {   // d=32: pair (lane, lane+32) once; never wraps -> local U, remote v
        const bool uw = true;
        const char* p = rowb + 1536 + 256;
        const uint2    a01 = *(const uint2*)(p);
        const uint2    a23 = *(const uint2*)(p + 512);
        const unsigned a4  = *(const unsigned*)(p + 1024);
        const uint2    c01 = *(const uint2*)(p + 3072);
        const uint2    c23 = *(const uint2*)(p + 3584);
        const unsigned c4  = *(const unsigned*)(p + 4096);
        PROC(0, a01.x, a01.y, a23.x, a23.y, a4);
        PROC(1, c01.x, c01.y, c23.x, c23.y, c4);
    }
    PROMOTE();

    // ================= epilogue: psi2 (linear) then DPP-reduce 5 per sample =================
    #pragma unroll
    for (int k = 0; k < 2; ++k) {
        float sv[10];
        #pragma unroll
        for (int j = 0; j < 5; ++j) { sv[2 * j] = S32[k][j].x; sv[2 * j + 1] = S32[k][j].y; }
        float po[5];
        #pragma unroll
        for (int o = 0; o < 5; ++o) {
            float acc = 0.0f;
            #pragma unroll
            for (int hh = 0; hh < 10; ++hh)
                acc = fmaf(sv[hh], psi_W2[hh * 5 + o], acc);
            po[o] = wave_sum63(acc);
        }
        if (lane == 63) {
            #pragma unroll
            for (int o = 0; o < 5; ++o)
                out[(b0 + k) * 5 + o] = fmaf(NPAIRF, psi_b2[o], po[o]);
        }
    }
    #undef PROC
    #undef PROMOTE
}

extern "C" void kernel_launch(void* const* d_in, const int* in_sizes, int n_in,
                              void* d_out, int out_size, void* d_ws, size_t ws_size,
                              hipStream_t stream) {
    const float* x      = (const float*)d_in[0];
    const float* phi_W1 = (const float*)d_in[1];
    const float* phi_b1 = (const float*)d_in[2];
    const float* phi_W2 = (const float*)d_in[3];
    const float* phi_b2 = (const float*)d_in[4];
    const float* attn_W = (const float*)d_in[5];
    const float* attn_b = (const float*)d_in[6];
    const float* psi_W1 = (const float*)d_in[7];
    const float* psi_b1 = (const float*)d_in[8];
    const float* psi_W2 = (const float*)d_in[9];
    const float* psi_b2 = (const float*)d_in[10];
    float* outp = (float*)d_out;

    dim3 grid(BATCH / 8);   // 4 waves/block x 2 samples/wave
    dim3 block(256);
    akan_kernel<<<grid, block, 0, stream>>>(x, phi_W1, phi_b1, phi_W2, phi_b2,
                                            attn_W, attn_b, psi_W1, psi_b1,
                                            psi_W2, psi_b2, outp);
}